// Round 1
// baseline (898.953 us; speedup 1.0000x reference)
//
#include <hip/hip_runtime.h>

#define N_NODES 50000
#define N_EDGES 800000
#define DIM 64
#define N_LAYERS 3
#define N_GRAPHS 256
#define BN_EPS 1e-5f
#define TM 8

// ---------------------------------------------------------------- copy z = h
__global__ __launch_bounds__(256) void copy_kernel(const float* __restrict__ in,
                                                   float* __restrict__ out, int n4) {
    int i = blockIdx.x * 256 + threadIdx.x;
    if (i < n4) ((float4*)out)[i] = ((const float4*)in)[i];
}

// ------------------------------------------------- scatter: z[dst] += h[src]
// one wave per edge, lane = feature dim (256B coalesced gather per edge)
__global__ __launch_bounds__(256) void scatter_kernel(const float* __restrict__ h,
                                                      float* __restrict__ z,
                                                      const int* __restrict__ src,
                                                      const int* __restrict__ dst) {
    int e = blockIdx.x * 4 + (threadIdx.x >> 6);
    if (e >= N_EDGES) return;
    int lane = threadIdx.x & 63;
    int s = src[e], d = dst[e];
    atomicAdd(&z[(size_t)d * DIM + lane], h[(size_t)s * DIM + lane]);
}

// ---------------------- fused MLP (relu(zW1+B1)W2+B2, relu) + BN stat sums
// block = 4 waves; each wave owns TM=8 rows; lane = output column.
__global__ __launch_bounds__(256) void mlp_stats_kernel(float* __restrict__ z,
    const float* __restrict__ W1, const float* __restrict__ B1,
    const float* __restrict__ W2, const float* __restrict__ B2,
    float* __restrict__ sums) {
    __shared__ float sW1[DIM * DIM];
    __shared__ float sW2[DIM * DIM];
    __shared__ float sB1[DIM], sB2[DIM];
    __shared__ float sZ[4][TM * DIM];
    __shared__ float sRed[2][256];

    int tid = threadIdx.x;
    for (int i = tid; i < DIM * DIM / 4; i += 256) {
        ((float4*)sW1)[i] = ((const float4*)W1)[i];
        ((float4*)sW2)[i] = ((const float4*)W2)[i];
    }
    if (tid < DIM) { sB1[tid] = B1[tid]; sB2[tid] = B2[tid]; }

    int wave = tid >> 6, lane = tid & 63;
    int tile = blockIdx.x * 4 + wave;
    int row0 = tile * TM;
    bool active = (row0 < N_NODES);           // wave-uniform (50000 % 8 == 0)
    float* zs = sZ[wave];

    if (active) {                              // stage 8 rows (coalesced f4)
        const float4* zg = (const float4*)(z + (size_t)row0 * DIM);
        ((float4*)zs)[lane]      = zg[lane];
        ((float4*)zs)[lane + 64] = zg[lane + 64];
    }
    __syncthreads();   // also covers weight staging

    float t[TM];
    if (active) {
        float acc[TM];
#pragma unroll
        for (int r = 0; r < TM; r++) acc[r] = sB1[lane];
#pragma unroll
        for (int kc = 0; kc < DIM / 4; kc++) {
            int k = kc * 4;
            float w0 = sW1[(k + 0) * DIM + lane];
            float w1 = sW1[(k + 1) * DIM + lane];
            float w2 = sW1[(k + 2) * DIM + lane];
            float w3 = sW1[(k + 3) * DIM + lane];
#pragma unroll
            for (int r = 0; r < TM; r++) {
                float4 zb = *(const float4*)&zs[r * DIM + k];   // broadcast
                acc[r] = fmaf(zb.x, w0, acc[r]);
                acc[r] = fmaf(zb.y, w1, acc[r]);
                acc[r] = fmaf(zb.z, w2, acc[r]);
                acc[r] = fmaf(zb.w, w3, acc[r]);
            }
        }
#pragma unroll
        for (int r = 0; r < TM; r++) t[r] = fmaxf(acc[r], 0.f);
        // overwrite our wave's slice with the hidden activations
#pragma unroll
        for (int r = 0; r < TM; r++) zs[r * DIM + lane] = t[r];
    }
    __syncthreads();

    float ssum = 0.f, ssq = 0.f;
    if (active) {
        float acc[TM];
#pragma unroll
        for (int r = 0; r < TM; r++) acc[r] = sB2[lane];
#pragma unroll
        for (int kc = 0; kc < DIM / 4; kc++) {
            int k = kc * 4;
            float w0 = sW2[(k + 0) * DIM + lane];
            float w1 = sW2[(k + 1) * DIM + lane];
            float w2 = sW2[(k + 2) * DIM + lane];
            float w3 = sW2[(k + 3) * DIM + lane];
#pragma unroll
            for (int r = 0; r < TM; r++) {
                float4 zb = *(const float4*)&zs[r * DIM + k];
                acc[r] = fmaf(zb.x, w0, acc[r]);
                acc[r] = fmaf(zb.y, w1, acc[r]);
                acc[r] = fmaf(zb.z, w2, acc[r]);
                acc[r] = fmaf(zb.w, w3, acc[r]);
            }
        }
#pragma unroll
        for (int r = 0; r < TM; r++) {
            float v = fmaxf(acc[r], 0.f);
            z[(size_t)(row0 + r) * DIM + lane] = v;
            ssum += v;
            ssq  = fmaf(v, v, ssq);
        }
    }
    sRed[0][tid] = ssum;
    sRed[1][tid] = ssq;
    __syncthreads();
    if (wave == 0) {
        float a = sRed[0][lane] + sRed[0][64 + lane] + sRed[0][128 + lane] + sRed[0][192 + lane];
        float b = sRed[1][lane] + sRed[1][64 + lane] + sRed[1][128 + lane] + sRed[1][192 + lane];
        atomicAdd(&sums[lane], a);
        atomicAdd(&sums[DIM + lane], b);
    }
}

// --------------------------------------------- BN scale/shift from sums
__global__ void finalize_stats(const float* __restrict__ sums,
                               const float* __restrict__ gamma,
                               const float* __restrict__ beta,
                               float* __restrict__ ss) {
    int c = threadIdx.x;
    const float inv_n = 1.0f / (float)N_NODES;
    float mu  = sums[c] * inv_n;
    float var = sums[DIM + c] * inv_n - mu * mu;
    float sc  = gamma[c] / sqrtf(var + BN_EPS);
    ss[c]       = sc;
    ss[DIM + c] = beta[c] - mu * sc;
}

// ----------------------------- BN apply (in place) + global_add_pool
__global__ __launch_bounds__(256) void bn_pool_kernel(float* __restrict__ z,
    const float* __restrict__ ss, const int* __restrict__ batch,
    float* __restrict__ pooled, int layer) {
    int idx = blockIdx.x * 256 + threadIdx.x;
    if (idx >= N_NODES * DIM) return;
    int node = idx >> 6, c = idx & 63;
    float v = fmaf(z[idx], ss[c], ss[DIM + c]);
    z[idx] = v;
    atomicAdd(&pooled[(size_t)batch[node] * (DIM * N_LAYERS) + layer * DIM + c], v);
}

// ------------------------------------------------ final 2-layer MLP on pooled
__global__ __launch_bounds__(192) void final_mlp(const float* __restrict__ pooled,
    const float* __restrict__ PW1, const float* __restrict__ PB1,
    const float* __restrict__ PW2, const float* __restrict__ PB2,
    float* __restrict__ out) {
    __shared__ float row[DIM * N_LAYERS];
    __shared__ float hid[DIM * N_LAYERS];
    const int D3 = DIM * N_LAYERS;
    int g = blockIdx.x, j = threadIdx.x;
    row[j] = pooled[(size_t)g * D3 + j];
    __syncthreads();
    float acc = PB1[j];
    for (int k = 0; k < D3; k++) acc = fmaf(row[k], PW1[k * D3 + j], acc);
    hid[j] = fmaxf(acc, 0.f);
    __syncthreads();
    float acc2 = PB2[j];
    for (int k = 0; k < D3; k++) acc2 = fmaf(hid[k], PW2[k * D3 + j], acc2);
    out[(size_t)g * D3 + j] = acc2;
}

extern "C" void kernel_launch(void* const* d_in, const int* in_sizes, int n_in,
                              void* d_out, int out_size, void* d_ws, size_t ws_size,
                              hipStream_t stream) {
    const float* x     = (const float*)d_in[0];
    const int*   ei    = (const int*)d_in[1];
    const int*   batch = (const int*)d_in[2];
    const float* W1    = (const float*)d_in[3];
    const float* B1    = (const float*)d_in[4];
    const float* W2    = (const float*)d_in[5];
    const float* B2    = (const float*)d_in[6];
    const float* gamma = (const float*)d_in[7];
    const float* beta  = (const float*)d_in[8];
    const float* PW1   = (const float*)d_in[9];
    const float* PB1   = (const float*)d_in[10];
    const float* PW2   = (const float*)d_in[11];
    const float* PB2   = (const float*)d_in[12];
    float* out = (float*)d_out;

    float* bufA   = (float*)d_ws;
    float* bufB   = bufA + (size_t)N_NODES * DIM;
    float* pooled = bufB + (size_t)N_NODES * DIM;
    float* sums   = pooled + N_GRAPHS * DIM * N_LAYERS;   // 3 * 128 floats
    float* ssbuf  = sums + N_LAYERS * 2 * DIM;            // 3 * 128 floats

    const int* src = ei;
    const int* dst = ei + N_EDGES;

    hipMemsetAsync(pooled, 0,
                   (N_GRAPHS * DIM * N_LAYERS + N_LAYERS * 2 * DIM) * sizeof(float),
                   stream);

    const float* P = x;
    float* Q = bufA;
    for (int L = 0; L < N_LAYERS; ++L) {
        copy_kernel<<<(N_NODES * DIM / 4 + 255) / 256, 256, 0, stream>>>(P, Q, N_NODES * DIM / 4);
        scatter_kernel<<<N_EDGES / 4, 256, 0, stream>>>(P, Q, src, dst);
        mlp_stats_kernel<<<((N_NODES / TM) + 3) / 4, 256, 0, stream>>>(
            Q, W1 + (size_t)L * DIM * DIM, B1 + (size_t)L * DIM,
            W2 + (size_t)L * DIM * DIM, B2 + (size_t)L * DIM,
            sums + (size_t)L * 2 * DIM);
        finalize_stats<<<1, DIM, 0, stream>>>(sums + (size_t)L * 2 * DIM,
                                              gamma + (size_t)L * DIM,
                                              beta + (size_t)L * DIM,
                                              ssbuf + (size_t)L * 2 * DIM);
        bn_pool_kernel<<<(N_NODES * DIM + 255) / 256, 256, 0, stream>>>(
            Q, ssbuf + (size_t)L * 2 * DIM, batch, pooled, L);
        P = Q;
        Q = (Q == bufA) ? bufB : bufA;
    }
    final_mlp<<<N_GRAPHS, 192, 0, stream>>>(pooled, PW1, PB1, PW2, PB2, out);
}

// Round 2
// 508.636 us; speedup vs baseline: 1.7674x; 1.7674x over previous
//
#include <hip/hip_runtime.h>

#define N_NODES 50000
#define N_EDGES 800000
#define DIM 64
#define N_LAYERS 3
#define N_GRAPHS 256
#define BN_EPS 1e-5f
#define TM 8
#define D3 (DIM * N_LAYERS)

// ------------------------------------------------------------ CSR build
__global__ __launch_bounds__(256) void hist_kernel(const int* __restrict__ dst,
                                                   int* __restrict__ deg) {
    int e = blockIdx.x * 256 + threadIdx.x;
    if (e < N_EDGES) atomicAdd(&deg[dst[e]], 1);
}

__global__ __launch_bounds__(256) void scan_partial(const int* __restrict__ deg,
                                                    int* __restrict__ rp,
                                                    int* __restrict__ bsum) {
    __shared__ int s[256];
    int i = blockIdx.x * 256 + threadIdx.x;
    int v = (i < N_NODES) ? deg[i] : 0;
    s[threadIdx.x] = v;
    __syncthreads();
    for (int off = 1; off < 256; off <<= 1) {
        int t = (threadIdx.x >= off) ? s[threadIdx.x - off] : 0;
        __syncthreads();
        s[threadIdx.x] += t;
        __syncthreads();
    }
    if (i < N_NODES) rp[i] = s[threadIdx.x] - v;          // exclusive
    if (threadIdx.x == 255) bsum[blockIdx.x] = s[255];
}

__global__ __launch_bounds__(256) void scan_bsum(int* __restrict__ bsum, int nblk) {
    __shared__ int s[256];
    int v = (threadIdx.x < nblk) ? bsum[threadIdx.x] : 0;
    s[threadIdx.x] = v;
    __syncthreads();
    for (int off = 1; off < 256; off <<= 1) {
        int t = (threadIdx.x >= off) ? s[threadIdx.x - off] : 0;
        __syncthreads();
        s[threadIdx.x] += t;
        __syncthreads();
    }
    if (threadIdx.x < nblk) bsum[threadIdx.x] = s[threadIdx.x] - v;  // exclusive
}

__global__ __launch_bounds__(256) void scan_fixup(int* __restrict__ rp,
                                                  const int* __restrict__ bsum) {
    int i = blockIdx.x * 256 + threadIdx.x;
    if (i < N_NODES) rp[i] += bsum[blockIdx.x];
    if (i == 0) rp[N_NODES] = N_EDGES;
}

__global__ __launch_bounds__(256) void fill_csr(const int* __restrict__ src,
                                                const int* __restrict__ dst,
                                                const int* __restrict__ rp,
                                                int* __restrict__ cnt,
                                                int* __restrict__ csr) {
    int e = blockIdx.x * 256 + threadIdx.x;
    if (e >= N_EDGES) return;
    int d = dst[e];
    int pos = rp[d] + atomicAdd(&cnt[d], 1);
    csr[pos] = src[e];
}

// ------------------------------- gather: z[i] = h[i] + sum_{j->i} h[j]
// one wave per node, lane = feature
__global__ __launch_bounds__(256) void gather_kernel(const float* __restrict__ h,
                                                     float* __restrict__ z,
                                                     const int* __restrict__ rp,
                                                     const int* __restrict__ csr) {
    int node = blockIdx.x * 4 + (threadIdx.x >> 6);
    if (node >= N_NODES) return;
    int lane = threadIdx.x & 63;
    float acc = h[(size_t)node * DIM + lane];
    int e = rp[node], end = rp[node + 1];
    for (; e + 4 <= end; e += 4) {
        int s0 = csr[e], s1 = csr[e + 1], s2 = csr[e + 2], s3 = csr[e + 3];
        float v0 = h[(size_t)s0 * DIM + lane];
        float v1 = h[(size_t)s1 * DIM + lane];
        float v2 = h[(size_t)s2 * DIM + lane];
        float v3 = h[(size_t)s3 * DIM + lane];
        acc += (v0 + v1) + (v2 + v3);
    }
    for (; e < end; e++) acc += h[(size_t)csr[e] * DIM + lane];
    z[(size_t)node * DIM + lane] = acc;
}

// ---------------------- fused MLP (relu(zW1+B1)W2+B2, relu) + BN stat sums
__global__ __launch_bounds__(256) void mlp_stats_kernel(float* __restrict__ z,
    const float* __restrict__ W1, const float* __restrict__ B1,
    const float* __restrict__ W2, const float* __restrict__ B2,
    float* __restrict__ sums) {
    __shared__ float sW1[DIM * DIM];
    __shared__ float sW2[DIM * DIM];
    __shared__ float sB1[DIM], sB2[DIM];
    __shared__ float sZ[4][TM * DIM];
    __shared__ float sRed[2][256];

    int tid = threadIdx.x;
    for (int i = tid; i < DIM * DIM / 4; i += 256) {
        ((float4*)sW1)[i] = ((const float4*)W1)[i];
        ((float4*)sW2)[i] = ((const float4*)W2)[i];
    }
    if (tid < DIM) { sB1[tid] = B1[tid]; sB2[tid] = B2[tid]; }

    int wave = tid >> 6, lane = tid & 63;
    int tile = blockIdx.x * 4 + wave;
    int row0 = tile * TM;
    bool active = (row0 < N_NODES);           // wave-uniform (50000 % 8 == 0)
    float* zs = sZ[wave];

    if (active) {
        const float4* zg = (const float4*)(z + (size_t)row0 * DIM);
        ((float4*)zs)[lane]      = zg[lane];
        ((float4*)zs)[lane + 64] = zg[lane + 64];
    }
    __syncthreads();

    float t[TM];
    if (active) {
        float acc[TM];
#pragma unroll
        for (int r = 0; r < TM; r++) acc[r] = sB1[lane];
#pragma unroll
        for (int kc = 0; kc < DIM / 4; kc++) {
            int k = kc * 4;
            float w0 = sW1[(k + 0) * DIM + lane];
            float w1 = sW1[(k + 1) * DIM + lane];
            float w2 = sW1[(k + 2) * DIM + lane];
            float w3 = sW1[(k + 3) * DIM + lane];
#pragma unroll
            for (int r = 0; r < TM; r++) {
                float4 zb = *(const float4*)&zs[r * DIM + k];
                acc[r] = fmaf(zb.x, w0, acc[r]);
                acc[r] = fmaf(zb.y, w1, acc[r]);
                acc[r] = fmaf(zb.z, w2, acc[r]);
                acc[r] = fmaf(zb.w, w3, acc[r]);
            }
        }
#pragma unroll
        for (int r = 0; r < TM; r++) t[r] = fmaxf(acc[r], 0.f);
#pragma unroll
        for (int r = 0; r < TM; r++) zs[r * DIM + lane] = t[r];
    }
    __syncthreads();

    float ssum = 0.f, ssq = 0.f;
    if (active) {
        float acc[TM];
#pragma unroll
        for (int r = 0; r < TM; r++) acc[r] = sB2[lane];
#pragma unroll
        for (int kc = 0; kc < DIM / 4; kc++) {
            int k = kc * 4;
            float w0 = sW2[(k + 0) * DIM + lane];
            float w1 = sW2[(k + 1) * DIM + lane];
            float w2 = sW2[(k + 2) * DIM + lane];
            float w3 = sW2[(k + 3) * DIM + lane];
#pragma unroll
            for (int r = 0; r < TM; r++) {
                float4 zb = *(const float4*)&zs[r * DIM + k];
                acc[r] = fmaf(zb.x, w0, acc[r]);
                acc[r] = fmaf(zb.y, w1, acc[r]);
                acc[r] = fmaf(zb.z, w2, acc[r]);
                acc[r] = fmaf(zb.w, w3, acc[r]);
            }
        }
#pragma unroll
        for (int r = 0; r < TM; r++) {
            float v = fmaxf(acc[r], 0.f);
            z[(size_t)(row0 + r) * DIM + lane] = v;
            ssum += v;
            ssq  = fmaf(v, v, ssq);
        }
    }
    sRed[0][tid] = ssum;
    sRed[1][tid] = ssq;
    __syncthreads();
    if (wave == 0) {
        float a = sRed[0][lane] + sRed[0][64 + lane] + sRed[0][128 + lane] + sRed[0][192 + lane];
        float b = sRed[1][lane] + sRed[1][64 + lane] + sRed[1][128 + lane] + sRed[1][192 + lane];
        atomicAdd(&sums[lane], a);
        atomicAdd(&sums[DIM + lane], b);
    }
}

// --------------------------------------------- BN scale/shift from sums
__global__ void finalize_stats(const float* __restrict__ sums,
                               const float* __restrict__ gamma,
                               const float* __restrict__ beta,
                               float* __restrict__ ss) {
    int c = threadIdx.x;
    const float inv_n = 1.0f / (float)N_NODES;
    float mu  = sums[c] * inv_n;
    float var = sums[DIM + c] * inv_n - mu * mu;
    float sc  = gamma[c] / sqrtf(var + BN_EPS);
    ss[c]       = sc;
    ss[DIM + c] = beta[c] - mu * sc;
}

// ----------------------------- BN apply (in place) + global_add_pool
// batch is SORTED: accumulate runs in registers, flush one atomic per
// graph-change. Each thread handles channel c for 8 consecutive nodes.
__global__ __launch_bounds__(256) void bn_pool_kernel(float* __restrict__ z,
    const float* __restrict__ ss, const int* __restrict__ batch,
    float* __restrict__ pooled, int layer) {
    int grp = blockIdx.x * 4 + (threadIdx.x >> 6);   // node group of 8
    if (grp >= N_NODES / 8) return;
    int c = threadIdx.x & 63;
    int n0 = grp * 8;
    float sc = ss[c], sh = ss[DIM + c];
    float run = 0.f;
    int cur = batch[n0];
#pragma unroll
    for (int r = 0; r < 8; r++) {
        int n = n0 + r;
        float v = fmaf(z[(size_t)n * DIM + c], sc, sh);
        z[(size_t)n * DIM + c] = v;
        int b = batch[n];
        if (b != cur) {
            atomicAdd(&pooled[(size_t)cur * D3 + layer * DIM + c], run);
            run = 0.f;
            cur = b;
        }
        run += v;
    }
    atomicAdd(&pooled[(size_t)cur * D3 + layer * DIM + c], run);
}

// ------------------------------------------------ final 2-layer MLP on pooled
__global__ __launch_bounds__(192) void final_mlp(const float* __restrict__ pooled,
    const float* __restrict__ PW1, const float* __restrict__ PB1,
    const float* __restrict__ PW2, const float* __restrict__ PB2,
    float* __restrict__ out) {
    __shared__ float row[D3];
    __shared__ float hid[D3];
    int g = blockIdx.x, j = threadIdx.x;
    row[j] = pooled[(size_t)g * D3 + j];
    __syncthreads();
    float acc = PB1[j];
    for (int k = 0; k < D3; k++) acc = fmaf(row[k], PW1[k * D3 + j], acc);
    hid[j] = fmaxf(acc, 0.f);
    __syncthreads();
    float acc2 = PB2[j];
    for (int k = 0; k < D3; k++) acc2 = fmaf(hid[k], PW2[k * D3 + j], acc2);
    out[(size_t)g * D3 + j] = acc2;
}

extern "C" void kernel_launch(void* const* d_in, const int* in_sizes, int n_in,
                              void* d_out, int out_size, void* d_ws, size_t ws_size,
                              hipStream_t stream) {
    const float* x     = (const float*)d_in[0];
    const int*   ei    = (const int*)d_in[1];
    const int*   batch = (const int*)d_in[2];
    const float* W1    = (const float*)d_in[3];
    const float* B1    = (const float*)d_in[4];
    const float* W2    = (const float*)d_in[5];
    const float* B2    = (const float*)d_in[6];
    const float* gamma = (const float*)d_in[7];
    const float* beta  = (const float*)d_in[8];
    const float* PW1   = (const float*)d_in[9];
    const float* PB1   = (const float*)d_in[10];
    const float* PW2   = (const float*)d_in[11];
    const float* PB2   = (const float*)d_in[12];
    float* out = (float*)d_out;

    // -------- workspace layout
    float* bufA   = (float*)d_ws;                         // 3,200,000 f
    float* bufB   = bufA + (size_t)N_NODES * DIM;         // 3,200,000 f
    int*   csr    = (int*)(bufB + (size_t)N_NODES * DIM); // 800,000 i
    int*   rp     = csr + N_EDGES;                        // 50,001 i
    int*   bsum   = rp + (N_NODES + 1);                   // 256 i
    int*   deg    = bsum + 256;                           // 50,000 i  <- zero from here
    int*   cnt    = deg + N_NODES;                        // 50,000 i
    float* pooled = (float*)(cnt + N_NODES);              // 49,152 f
    float* sums   = pooled + N_GRAPHS * D3;               // 384 f     <- zero to here
    float* ssbuf  = sums + N_LAYERS * 2 * DIM;            // 384 f

    const int* src = ei;
    const int* dst = ei + N_EDGES;

    const size_t zero_bytes =
        (size_t)(2 * N_NODES) * sizeof(int) +
        (size_t)(N_GRAPHS * D3 + N_LAYERS * 2 * DIM) * sizeof(float);
    hipMemsetAsync(deg, 0, zero_bytes, stream);

    // -------- CSR build (incoming edges per node)
    const int EB = (N_EDGES + 255) / 256;        // 3125
    const int NB = (N_NODES + 255) / 256;        // 196
    hist_kernel<<<EB, 256, 0, stream>>>(dst, deg);
    scan_partial<<<NB, 256, 0, stream>>>(deg, rp, bsum);
    scan_bsum<<<1, 256, 0, stream>>>(bsum, NB);
    scan_fixup<<<NB, 256, 0, stream>>>(rp, bsum);
    fill_csr<<<EB, 256, 0, stream>>>(src, dst, rp, cnt, csr);

    // -------- layers
    const float* P = x;
    float* Q = bufA;
    for (int L = 0; L < N_LAYERS; ++L) {
        gather_kernel<<<(N_NODES + 3) / 4, 256, 0, stream>>>(P, Q, rp, csr);
        mlp_stats_kernel<<<((N_NODES / TM) + 3) / 4, 256, 0, stream>>>(
            Q, W1 + (size_t)L * DIM * DIM, B1 + (size_t)L * DIM,
            W2 + (size_t)L * DIM * DIM, B2 + (size_t)L * DIM,
            sums + (size_t)L * 2 * DIM);
        finalize_stats<<<1, DIM, 0, stream>>>(sums + (size_t)L * 2 * DIM,
                                              gamma + (size_t)L * DIM,
                                              beta + (size_t)L * DIM,
                                              ssbuf + (size_t)L * 2 * DIM);
        bn_pool_kernel<<<(N_NODES / 8 + 3) / 4, 256, 0, stream>>>(
            Q, ssbuf + (size_t)L * 2 * DIM, batch, pooled, L);
        P = Q;
        Q = (Q == bufA) ? bufB : bufA;
    }
    final_mlp<<<N_GRAPHS, 192, 0, stream>>>(pooled, PW1, PB1, PW2, PB2, out);
}

// Round 3
// 375.890 us; speedup vs baseline: 2.3915x; 1.3531x over previous
//
#include <hip/hip_runtime.h>

#define N_NODES 50000
#define N_EDGES 800000
#define DIM 64
#define N_LAYERS 3
#define N_GRAPHS 256
#define BN_EPS 1e-5f
#define D3 (DIM * N_LAYERS)
#define N_PART 64   // partial BN-sum buffers (contention spreading)

typedef __attribute__((ext_vector_type(8))) short short8;
typedef __attribute__((ext_vector_type(4))) float floatx4;

// ---------------------------------------------------------- bf16 split utils
__device__ inline unsigned short bf16_rn(float f) {
    unsigned u = __float_as_uint(f);
    u += 0x7FFF + ((u >> 16) & 1);
    return (unsigned short)(u >> 16);
}
__device__ inline float bf16_f(unsigned short b) {
    return __uint_as_float(((unsigned)b) << 16);
}
// split 8 floats (two float4s) into hi/lo bf16 fragments
__device__ inline void split8(float4 a, float4 b, short8* hi, short8* lo) {
    float v[8] = {a.x, a.y, a.z, a.w, b.x, b.y, b.z, b.w};
#pragma unroll
    for (int i = 0; i < 8; i++) {
        unsigned short h = bf16_rn(v[i]);
        (*hi)[i] = (short)h;
        (*lo)[i] = (short)bf16_rn(v[i] - bf16_f(h));
    }
}

// ------------------------------------------------------------ CSR build
__global__ __launch_bounds__(256) void hist_kernel(const int* __restrict__ dst,
                                                   int* __restrict__ deg) {
    int e = blockIdx.x * 256 + threadIdx.x;
    if (e < N_EDGES) atomicAdd(&deg[dst[e]], 1);
}

__global__ __launch_bounds__(256) void scan_partial(const int* __restrict__ deg,
                                                    int* __restrict__ rp,
                                                    int* __restrict__ bsum) {
    __shared__ int s[256];
    int i = blockIdx.x * 256 + threadIdx.x;
    int v = (i < N_NODES) ? deg[i] : 0;
    s[threadIdx.x] = v;
    __syncthreads();
    for (int off = 1; off < 256; off <<= 1) {
        int t = (threadIdx.x >= off) ? s[threadIdx.x - off] : 0;
        __syncthreads();
        s[threadIdx.x] += t;
        __syncthreads();
    }
    if (i < N_NODES) rp[i] = s[threadIdx.x] - v;
    if (threadIdx.x == 255) bsum[blockIdx.x] = s[255];
}

__global__ __launch_bounds__(256) void scan_bsum(int* __restrict__ bsum, int nblk) {
    __shared__ int s[256];
    int v = (threadIdx.x < nblk) ? bsum[threadIdx.x] : 0;
    s[threadIdx.x] = v;
    __syncthreads();
    for (int off = 1; off < 256; off <<= 1) {
        int t = (threadIdx.x >= off) ? s[threadIdx.x - off] : 0;
        __syncthreads();
        s[threadIdx.x] += t;
        __syncthreads();
    }
    if (threadIdx.x < nblk) bsum[threadIdx.x] = s[threadIdx.x] - v;
}

__global__ __launch_bounds__(256) void scan_fixup(int* __restrict__ rp,
                                                  const int* __restrict__ bsum) {
    int i = blockIdx.x * 256 + threadIdx.x;
    if (i < N_NODES) rp[i] += bsum[blockIdx.x];
    if (i == 0) rp[N_NODES] = N_EDGES;
}

__global__ __launch_bounds__(256) void fill_csr(const int* __restrict__ src,
                                                const int* __restrict__ dst,
                                                const int* __restrict__ rp,
                                                int* __restrict__ cnt,
                                                int* __restrict__ csr) {
    int e = blockIdx.x * 256 + threadIdx.x;
    if (e >= N_EDGES) return;
    int d = dst[e];
    int pos = rp[d] + atomicAdd(&cnt[d], 1);
    csr[pos] = src[e];
}

// ------------------------------- gather: z[i] = h[i] + sum_{j->i} h[j]
__global__ __launch_bounds__(256) void gather_kernel(const float* __restrict__ h,
                                                     float* __restrict__ z,
                                                     const int* __restrict__ rp,
                                                     const int* __restrict__ csr) {
    int node = blockIdx.x * 4 + (threadIdx.x >> 6);
    if (node >= N_NODES) return;
    int lane = threadIdx.x & 63;
    float acc = h[(size_t)node * DIM + lane];
    int e = rp[node], end = rp[node + 1];
    for (; e + 4 <= end; e += 4) {
        int s0 = csr[e], s1 = csr[e + 1], s2 = csr[e + 2], s3 = csr[e + 3];
        float v0 = h[(size_t)s0 * DIM + lane];
        float v1 = h[(size_t)s1 * DIM + lane];
        float v2 = h[(size_t)s2 * DIM + lane];
        float v3 = h[(size_t)s3 * DIM + lane];
        acc += (v0 + v1) + (v2 + v3);
    }
    for (; e < end; e++) acc += h[(size_t)csr[e] * DIM + lane];
    z[(size_t)node * DIM + lane] = acc;
}

// --------------- pack W1/W2 into MFMA B-operand fragments, split bf16 hi/lo
// layout per (layer,gemm): [prec(2)][frag=ntile*2+kstep (8)][lane(64)][j(8)]
__global__ __launch_bounds__(256) void prep_weights(const float* __restrict__ W1,
                                                    const float* __restrict__ W2,
                                                    unsigned short* __restrict__ wf) {
    int idx = blockIdx.x * 256 + threadIdx.x;           // 3*2*4096 = 24576
    if (idx >= N_LAYERS * 2 * 4096) return;
    int j    = idx & 7;
    int lane = (idx >> 3) & 63;
    int ks   = (idx >> 9) & 1;
    int nt   = (idx >> 10) & 3;
    int gemm = (idx >> 12) & 1;
    int layer = idx >> 13;
    int n = nt * 16 + (lane & 15);
    int k = ks * 32 + (lane >> 4) * 8 + j;
    const float* W = (gemm ? W2 : W1) + (size_t)layer * DIM * DIM;
    float w = W[k * DIM + n];
    unsigned short hi = bf16_rn(w);
    unsigned short lo = bf16_rn(w - bf16_f(hi));
    size_t base = ((size_t)layer * 2 + gemm) * 8192;
    int f = nt * 2 + ks;
    wf[base + f * 512 + lane * 8 + j]        = hi;
    wf[base + 4096 + f * 512 + lane * 8 + j] = lo;
}

// ---------------- MFMA MLP: z = relu(relu(zW1+B1)W2+B2), + BN stat partials
// wave = 16 rows; block = 4 waves = 64 rows; split-bf16 (AhBh+AhBl+AlBh)
#define HS_STRIDE 68
__global__ __launch_bounds__(256) void mlp_mfma(float* __restrict__ z,
    const unsigned short* __restrict__ wfL,      // this layer's fragments
    const float* __restrict__ B1, const float* __restrict__ B2,
    float* __restrict__ sums_part) {
    __shared__ float sH[4][16 * HS_STRIDE];
    __shared__ float sSum[2 * DIM];

    int tid = threadIdx.x, wave = tid >> 6, lane = tid & 63;
    if (tid < 2 * DIM) sSum[tid] = 0.f;
    __syncthreads();

    int m = lane & 15, quad = lane >> 4;
    int row0 = blockIdx.x * 64 + wave * 16;
    int grow = row0 + m;
    int ar = grow < N_NODES ? grow : N_NODES - 1;

    // ---- A fragments for GEMM1 (k = quad*8 + j, ksteps 0/1)
    const float4* zr = (const float4*)(z + (size_t)ar * DIM);
    float4 a0 = zr[quad * 2],     a1 = zr[quad * 2 + 1];
    float4 a2 = zr[8 + quad * 2], a3 = zr[8 + quad * 2 + 1];
    short8 Ah0, Al0, Ah1, Al1;
    split8(a0, a1, &Ah0, &Al0);
    split8(a2, a3, &Ah1, &Al1);

    // ---- GEMM1
    floatx4 acc[4];
#pragma unroll
    for (int nt = 0; nt < 4; nt++) acc[nt] = (floatx4){0.f, 0.f, 0.f, 0.f};
#pragma unroll
    for (int nt = 0; nt < 4; nt++) {
#pragma unroll
        for (int ks = 0; ks < 2; ks++) {
            const short8 Bh = *(const short8*)(wfL + (nt * 2 + ks) * 512 + lane * 8);
            const short8 Bl = *(const short8*)(wfL + 4096 + (nt * 2 + ks) * 512 + lane * 8);
            short8 Ahf = ks ? Ah1 : Ah0;
            short8 Alf = ks ? Al1 : Al0;
            acc[nt] = __builtin_amdgcn_mfma_f32_16x16x32_bf16(Ahf, Bh, acc[nt], 0, 0, 0);
            acc[nt] = __builtin_amdgcn_mfma_f32_16x16x32_bf16(Ahf, Bl, acc[nt], 0, 0, 0);
            acc[nt] = __builtin_amdgcn_mfma_f32_16x16x32_bf16(Alf, Bh, acc[nt], 0, 0, 0);
        }
    }

    // ---- bias + relu, park hidden in wave-private LDS (C layout -> A layout)
    float* Hs = sH[wave];
#pragma unroll
    for (int nt = 0; nt < 4; nt++) {
        int col = nt * 16 + m;
        float b = B1[col];
#pragma unroll
        for (int r = 0; r < 4; r++) {
            int lr = quad * 4 + r;
            Hs[lr * HS_STRIDE + col] = fmaxf(acc[nt][r] + b, 0.f);
        }
    }
    // wave-internal LDS RAW: compiler inserts lgkmcnt wait (no barrier needed)
    float4 h0 = *(const float4*)&Hs[m * HS_STRIDE + quad * 8];
    float4 h1 = *(const float4*)&Hs[m * HS_STRIDE + quad * 8 + 4];
    float4 h2 = *(const float4*)&Hs[m * HS_STRIDE + 32 + quad * 8];
    float4 h3 = *(const float4*)&Hs[m * HS_STRIDE + 32 + quad * 8 + 4];
    short8 Hh0, Hl0, Hh1, Hl1;
    split8(h0, h1, &Hh0, &Hl0);
    split8(h2, h3, &Hh1, &Hl1);

    // ---- GEMM2
    floatx4 acc2[4];
#pragma unroll
    for (int nt = 0; nt < 4; nt++) acc2[nt] = (floatx4){0.f, 0.f, 0.f, 0.f};
    const unsigned short* wg2 = wfL + 8192;
#pragma unroll
    for (int nt = 0; nt < 4; nt++) {
#pragma unroll
        for (int ks = 0; ks < 2; ks++) {
            const short8 Bh = *(const short8*)(wg2 + (nt * 2 + ks) * 512 + lane * 8);
            const short8 Bl = *(const short8*)(wg2 + 4096 + (nt * 2 + ks) * 512 + lane * 8);
            short8 Ahf = ks ? Hh1 : Hh0;
            short8 Alf = ks ? Hl1 : Hl0;
            acc2[nt] = __builtin_amdgcn_mfma_f32_16x16x32_bf16(Ahf, Bh, acc2[nt], 0, 0, 0);
            acc2[nt] = __builtin_amdgcn_mfma_f32_16x16x32_bf16(Ahf, Bl, acc2[nt], 0, 0, 0);
            acc2[nt] = __builtin_amdgcn_mfma_f32_16x16x32_bf16(Alf, Bh, acc2[nt], 0, 0, 0);
        }
    }

    // ---- bias + relu + store + BN partial sums
#pragma unroll
    for (int nt = 0; nt < 4; nt++) {
        int col = nt * 16 + m;
        float b = B2[col];
        float s = 0.f, s2 = 0.f;
#pragma unroll
        for (int r = 0; r < 4; r++) {
            int gr = row0 + quad * 4 + r;
            float v = fmaxf(acc2[nt][r] + b, 0.f);
            if (gr < N_NODES) {
                z[(size_t)gr * DIM + col] = v;
                s += v;
                s2 = fmaf(v, v, s2);
            }
        }
        s  += __shfl_xor(s, 16);  s  += __shfl_xor(s, 32);
        s2 += __shfl_xor(s2, 16); s2 += __shfl_xor(s2, 32);
        if (quad == 0) {
            atomicAdd(&sSum[col], s);
            atomicAdd(&sSum[DIM + col], s2);
        }
    }
    __syncthreads();
    if (tid < 2 * DIM)
        atomicAdd(&sums_part[(size_t)(blockIdx.x & (N_PART - 1)) * 2 * DIM + tid], sSum[tid]);
}

// --------------------------------------------- BN scale/shift from partials
__global__ void finalize_stats(const float* __restrict__ sp,
                               const float* __restrict__ gamma,
                               const float* __restrict__ beta,
                               float* __restrict__ ss) {
    int c = threadIdx.x;   // 64 threads
    float s = 0.f, q = 0.f;
    for (int p = 0; p < N_PART; p++) {
        s += sp[p * 2 * DIM + c];
        q += sp[p * 2 * DIM + DIM + c];
    }
    const float inv_n = 1.0f / (float)N_NODES;
    float mu  = s * inv_n;
    float var = q * inv_n - mu * mu;
    float sc  = gamma[c] / sqrtf(var + BN_EPS);
    ss[c]       = sc;
    ss[DIM + c] = beta[c] - mu * sc;
}

// ----------------------------- BN apply (in place) + global_add_pool
__global__ __launch_bounds__(256) void bn_pool_kernel(float* __restrict__ z,
    const float* __restrict__ ss, const int* __restrict__ batch,
    float* __restrict__ pooled, int layer) {
    int grp = blockIdx.x * 4 + (threadIdx.x >> 6);
    if (grp >= N_NODES / 8) return;
    int c = threadIdx.x & 63;
    int n0 = grp * 8;
    float sc = ss[c], sh = ss[DIM + c];
    float run = 0.f;
    int cur = batch[n0];
#pragma unroll
    for (int r = 0; r < 8; r++) {
        int n = n0 + r;
        float v = fmaf(z[(size_t)n * DIM + c], sc, sh);
        z[(size_t)n * DIM + c] = v;
        int b = batch[n];
        if (b != cur) {
            atomicAdd(&pooled[(size_t)cur * D3 + layer * DIM + c], run);
            run = 0.f;
            cur = b;
        }
        run += v;
    }
    atomicAdd(&pooled[(size_t)cur * D3 + layer * DIM + c], run);
}

// ------------------------------------------------ final 2-layer MLP on pooled
__global__ __launch_bounds__(192) void final_mlp(const float* __restrict__ pooled,
    const float* __restrict__ PW1, const float* __restrict__ PB1,
    const float* __restrict__ PW2, const float* __restrict__ PB2,
    float* __restrict__ out) {
    __shared__ float row[D3];
    __shared__ float hid[D3];
    int g = blockIdx.x, j = threadIdx.x;
    row[j] = pooled[(size_t)g * D3 + j];
    __syncthreads();
    float acc = PB1[j];
    for (int k = 0; k < D3; k++) acc = fmaf(row[k], PW1[k * D3 + j], acc);
    hid[j] = fmaxf(acc, 0.f);
    __syncthreads();
    float acc2 = PB2[j];
    for (int k = 0; k < D3; k++) acc2 = fmaf(hid[k], PW2[k * D3 + j], acc2);
    out[(size_t)g * D3 + j] = acc2;
}

extern "C" void kernel_launch(void* const* d_in, const int* in_sizes, int n_in,
                              void* d_out, int out_size, void* d_ws, size_t ws_size,
                              hipStream_t stream) {
    const float* x     = (const float*)d_in[0];
    const int*   ei    = (const int*)d_in[1];
    const int*   batch = (const int*)d_in[2];
    const float* W1    = (const float*)d_in[3];
    const float* B1    = (const float*)d_in[4];
    const float* W2    = (const float*)d_in[5];
    const float* B2    = (const float*)d_in[6];
    const float* gamma = (const float*)d_in[7];
    const float* beta  = (const float*)d_in[8];
    const float* PW1   = (const float*)d_in[9];
    const float* PB1   = (const float*)d_in[10];
    const float* PW2   = (const float*)d_in[11];
    const float* PB2   = (const float*)d_in[12];
    float* out = (float*)d_out;

    // -------- workspace layout (element offsets; keep 16B alignment)
    float* bufA      = (float*)d_ws;                          // 3,200,000 f
    float* bufB      = bufA + (size_t)N_NODES * DIM;          // 3,200,000 f
    int*   csr       = (int*)(bufB + (size_t)N_NODES * DIM);  // 800,000 i
    int*   rp        = csr + N_EDGES;                         // 50,008 i (padded)
    int*   bsum      = rp + 50008;                            // 256 i
    int*   deg       = bsum + 256;                            // 50,000 i  <- zero from
    int*   cnt       = deg + N_NODES;                         // 50,000 i
    float* pooled    = (float*)(cnt + N_NODES);               // 49,152 f
    float* sums_part = pooled + N_GRAPHS * D3;                // 3*64*128 f <- zero to
    float* ssbuf     = sums_part + N_LAYERS * N_PART * 2 * DIM;  // 384 f
    unsigned short* wfrag = (unsigned short*)(ssbuf + N_LAYERS * 2 * DIM); // 49,152 us

    const int* src = ei;
    const int* dst = ei + N_EDGES;

    const size_t zero_bytes =
        (size_t)(2 * N_NODES) * sizeof(int) +
        (size_t)(N_GRAPHS * D3 + N_LAYERS * N_PART * 2 * DIM) * sizeof(float);
    hipMemsetAsync(deg, 0, zero_bytes, stream);

    // -------- CSR build + weight prep
    const int EB = (N_EDGES + 255) / 256;
    const int NB = (N_NODES + 255) / 256;
    hist_kernel<<<EB, 256, 0, stream>>>(dst, deg);
    scan_partial<<<NB, 256, 0, stream>>>(deg, rp, bsum);
    scan_bsum<<<1, 256, 0, stream>>>(bsum, NB);
    scan_fixup<<<NB, 256, 0, stream>>>(rp, bsum);
    fill_csr<<<EB, 256, 0, stream>>>(src, dst, rp, cnt, csr);
    prep_weights<<<(N_LAYERS * 2 * 4096 + 255) / 256, 256, 0, stream>>>(W1, W2, wfrag);

    // -------- layers
    const float* P = x;
    float* Q = bufA;
    const int MB = (N_NODES + 63) / 64;   // 782 blocks (64 rows each)
    for (int L = 0; L < N_LAYERS; ++L) {
        gather_kernel<<<(N_NODES + 3) / 4, 256, 0, stream>>>(P, Q, rp, csr);
        mlp_mfma<<<MB, 256, 0, stream>>>(
            Q, wfrag + (size_t)L * 2 * 8192, B1 + (size_t)L * DIM, B2 + (size_t)L * DIM,
            sums_part + (size_t)L * N_PART * 2 * DIM);
        finalize_stats<<<1, DIM, 0, stream>>>(sums_part + (size_t)L * N_PART * 2 * DIM,
                                              gamma + (size_t)L * DIM,
                                              beta + (size_t)L * DIM,
                                              ssbuf + (size_t)L * 2 * DIM);
        bn_pool_kernel<<<(N_NODES / 8 + 3) / 4, 256, 0, stream>>>(
            Q, ssbuf + (size_t)L * 2 * DIM, batch, pooled, L);
        P = Q;
        Q = (Q == bufA) ? bufB : bufA;
    }
    final_mlp<<<N_GRAPHS, 192, 0, stream>>>(pooled, PW1, PB1, PW2, PB2, out);
}